// Round 1
// 463.167 us; speedup vs baseline: 1.0023x; 1.0023x over previous
//
#include <hip/hip_runtime.h>

#define LN_EPS 1e-5f

typedef _Float16 f16;
typedef _Float16 f16x4 __attribute__((ext_vector_type(4)));
typedef _Float16 f16x8 __attribute__((ext_vector_type(8)));
typedef float    f32x4 __attribute__((ext_vector_type(4)));

constexpr int KDIM = 192;
constexpr int NOUT = 256;
constexpr int XSTR = 200;   // f16 elems: 400B row stride, 16B-aligned, spreads b128 reads across banks

// ---------------------------------------------------------------------------
// Kernel W: fc_w fp32 -> f16 (one-time per launch; 49152 elems, 12288 float4)
// ---------------------------------------------------------------------------
__global__ __launch_bounds__(256)
void ut_wconv_kernel(const float* __restrict__ fc_w, f16* __restrict__ W16)
{
    const int i = blockIdx.x * 256 + threadIdx.x;     // 0..12287
    const float4 v = ((const float4*)fc_w)[i];
    f16x4 h = { (f16)v.x, (f16)v.y, (f16)v.z, (f16)v.w };
    ((f16x4*)W16)[i] = h;
}

// ---------------------------------------------------------------------------
// Fused kernel: gather + pool -> LDS (16 rows x 192 f16), one barrier, then
// FC 192->256 via f16 MFMA + ReLU + LayerNorm.  Block = 256 threads (4 waves).
// Gather phase: wave w produces rows w*4..w*4+3 (4 independent chains in
// flight per wave).  FC phase: identical to verified v4 structure, with A
// fragments read from LDS instead of a global X16 round-trip.
// ---------------------------------------------------------------------------
__global__ __launch_bounds__(256)
void ut_fused_kernel(const int*   __restrict__ user_input,
                     const float* __restrict__ emb,
                     const int*   __restrict__ sc_country_idx,
                     const float* __restrict__ sc_country_emb,
                     const int*   __restrict__ sc_device_idx,
                     const float* __restrict__ sc_device_emb,
                     const int*   __restrict__ mf_tags_idx,
                     const float* __restrict__ mf_tags_emb,
                     const int*   __restrict__ mf_history_idx,
                     const float* __restrict__ mf_history_emb,
                     const f16*   __restrict__ W16,
                     const float* __restrict__ fc_b,
                     const float* __restrict__ ln_g,
                     const float* __restrict__ ln_b,
                     float*       __restrict__ out,
                     int B)
{
    __shared__ f16   Xs[16][XSTR];
    __shared__ float sb[4][16];
    __shared__ float s2b[4][16];

    const int tid  = threadIdx.x;
    const int lane = tid & 63;
    const int wave = tid >> 6;
    const int row0 = blockIdx.x * 16;

    // ---- gather phase ----
    const int half = lane >> 5;                 // 0 or 1
    const int col  = lane & 31;                 // 0..31
    const int jt   = lane >> 3;                 // pooled-row slot 0..7
    const int fc   = lane & 7;                  // float4 chunk 0..7

    #pragma unroll
    for (int rr = 0; rr < 4; ++rr) {
        const int r16 = wave * 4 + rr;          // 0..15 within the block tile
        const int row = row0 + r16;
        if (row < B) {                          // wave-uniform predicate
            const int u = __builtin_amdgcn_readfirstlane(user_input[row]);

            const int ci = sc_country_idx[u];
            const int di = sc_device_idx[u];

            const int* __restrict__ tp = mf_tags_idx    + (size_t)u * 20;
            const int* __restrict__ hp = mf_history_idx + (size_t)u * 50;

            int  ti[3];  bool tv[3];
            #pragma unroll
            for (int p = 0; p < 3; ++p) {
                const int j = p * 8 + jt;
                tv[p] = (j < 20);
                ti[p] = tv[p] ? tp[j] : 0;
            }
            int  hi[7];  bool hv[7];
            #pragma unroll
            for (int p = 0; p < 7; ++p) {
                const int j = p * 8 + jt;
                hv[p] = (j < 50);
                hi[p] = hv[p] ? hp[j] : 0;
            }

            // main embedding: 64 floats, one per lane (256 B coalesced)
            const float e = emb[(size_t)u * 64 + lane];

            // scalar side features
            const float sc = (half == 0) ? sc_country_emb[ci * 32 + col]
                                         : sc_device_emb [di * 32 + col];

            // pooled gathers: independent, 1 KB useful bytes per instruction
            float4 ta4 = make_float4(0.f, 0.f, 0.f, 0.f);
            #pragma unroll
            for (int p = 0; p < 3; ++p) {
                const float4 g = *(const float4*)&mf_tags_emb[(size_t)ti[p] * 32 + fc * 4];
                if (tv[p]) { ta4.x += g.x; ta4.y += g.y; ta4.z += g.z; ta4.w += g.w; }
            }
            float4 ha4 = make_float4(0.f, 0.f, 0.f, 0.f);
            #pragma unroll
            for (int p = 0; p < 7; ++p) {
                const float4 g = *(const float4*)&mf_history_emb[(size_t)hi[p] * 32 + fc * 4];
                if (hv[p]) { ha4.x += g.x; ha4.y += g.y; ha4.z += g.z; ha4.w += g.w; }
            }

            // butterfly reduce across the 8 j-slots (lane bits 3,4,5)
            #pragma unroll
            for (int m = 8; m <= 32; m <<= 1) {
                ta4.x += __shfl_xor(ta4.x, m, 64);  ta4.y += __shfl_xor(ta4.y, m, 64);
                ta4.z += __shfl_xor(ta4.z, m, 64);  ta4.w += __shfl_xor(ta4.w, m, 64);
                ha4.x += __shfl_xor(ha4.x, m, 64);  ha4.y += __shfl_xor(ha4.y, m, 64);
                ha4.z += __shfl_xor(ha4.z, m, 64);  ha4.w += __shfl_xor(ha4.w, m, 64);
            }

            // write the 192-element f16 row into LDS
            Xs[r16][lane] = (f16)e;                         // cols 0..63
            if (half == 0) Xs[r16][64 + col] = (f16)sc;     // country: 64..95
            else           Xs[r16][96 + col] = (f16)sc;     // device:  96..127
            if (lane < 8) {
                const float s_t = 1.f / 20.f, s_h = 1.f / 50.f;
                f16x4 tq = { (f16)(ta4.x * s_t), (f16)(ta4.y * s_t),
                             (f16)(ta4.z * s_t), (f16)(ta4.w * s_t) };
                f16x4 hq = { (f16)(ha4.x * s_h), (f16)(ha4.y * s_h),
                             (f16)(ha4.z * s_h), (f16)(ha4.w * s_h) };
                *(f16x4*)&Xs[r16][128 + lane * 4] = tq;     // tags:    128..159
                *(f16x4*)&Xs[r16][160 + lane * 4] = hq;     // history: 160..191
            }
        }
    }
    __syncthreads();

    // ---- FC phase: wave w covers cols w*64..+63 as 4 col-tiles of 16 ----
    // A/B frags: frag[j] = M[lane&15][(lane>>4)*8 + j]; C/D: col = lane&15,
    // row = (lane>>4)*4 + reg   (m89-verified mapping, unchanged from v4).
    const int t    = lane & 15;
    const int quad = lane >> 4;
    const int colbase = wave * 64;

    f32x4 acc[4];
    #pragma unroll
    for (int ct = 0; ct < 4; ++ct) acc[ct] = (f32x4){0.f, 0.f, 0.f, 0.f};

    #pragma unroll
    for (int kt = 0; kt < 6; ++kt) {            // K = 192 = 6 * 32
        const f16x8 a = *(const f16x8*)&Xs[t][kt * 32 + quad * 8];
        #pragma unroll
        for (int ct = 0; ct < 4; ++ct) {
            const f16x8 b = *(const f16x8*)(W16 + (size_t)(colbase + ct * 16 + t) * KDIM
                                                 + kt * 32 + quad * 8);
            acc[ct] = __builtin_amdgcn_mfma_f32_16x16x32_f16(a, b, acc[ct], 0, 0, 0);
        }
    }

    // ---- epilogue: bias + ReLU, LN stats ----
    float bias[4], g4[4], bb4[4];
    #pragma unroll
    for (int ct = 0; ct < 4; ++ct) {
        const int c = colbase + ct * 16 + t;
        bias[ct] = fc_b[c];
        g4[ct]   = ln_g[c];
        bb4[ct]  = ln_b[c];
    }

    float y[4][4];
    float s[4]  = {0.f, 0.f, 0.f, 0.f};
    float s2[4] = {0.f, 0.f, 0.f, 0.f};
    #pragma unroll
    for (int ct = 0; ct < 4; ++ct) {
        #pragma unroll
        for (int r = 0; r < 4; ++r) {
            const float v = fmaxf(acc[ct][r] + bias[ct], 0.f);
            y[ct][r] = v;
            s[r]  += v;
            s2[r] += v * v;
        }
    }
    // reduce across the 16 t-lanes (lane bits 0..3); quad bits untouched
    #pragma unroll
    for (int m = 1; m <= 8; m <<= 1) {
        #pragma unroll
        for (int r = 0; r < 4; ++r) {
            s[r]  += __shfl_xor(s[r],  m, 64);
            s2[r] += __shfl_xor(s2[r], m, 64);
        }
    }
    if (t == 0) {
        #pragma unroll
        for (int r = 0; r < 4; ++r) {
            sb [wave][quad * 4 + r] = s[r];
            s2b[wave][quad * 4 + r] = s2[r];
        }
    }
    __syncthreads();

    #pragma unroll
    for (int r = 0; r < 4; ++r) {
        const int rho = quad * 4 + r;
        const float st  = sb [0][rho] + sb [1][rho] + sb [2][rho] + sb [3][rho];
        const float s2t = s2b[0][rho] + s2b[1][rho] + s2b[2][rho] + s2b[3][rho];
        const float mu  = st  * (1.f / 256.f);
        const float var = s2t * (1.f / 256.f) - mu * mu;
        const float rs  = rsqrtf(var + LN_EPS);
        if (row0 + rho < B) {
            #pragma unroll
            for (int ct = 0; ct < 4; ++ct) {
                const int c = colbase + ct * 16 + t;
                out[(size_t)(row0 + rho) * NOUT + c] = (y[ct][r] - mu) * rs * g4[ct] + bb4[ct];
            }
        }
    }
}

extern "C" void kernel_launch(void* const* d_in, const int* in_sizes, int n_in,
                              void* d_out, int out_size, void* d_ws, size_t ws_size,
                              hipStream_t stream)
{
    const int*   user_input     = (const int*)  d_in[0];
    const float* emb            = (const float*)d_in[1];
    const int*   sc_country_idx = (const int*)  d_in[2];
    const float* sc_country_emb = (const float*)d_in[3];
    const int*   sc_device_idx  = (const int*)  d_in[4];
    const float* sc_device_emb  = (const float*)d_in[5];
    const int*   mf_tags_idx    = (const int*)  d_in[6];
    const float* mf_tags_emb    = (const float*)d_in[7];
    const int*   mf_history_idx = (const int*)  d_in[8];
    const float* mf_history_emb = (const float*)d_in[9];
    const float* fc_w           = (const float*)d_in[10];
    const float* fc_b           = (const float*)d_in[11];
    const float* ln_g           = (const float*)d_in[12];
    const float* ln_b           = (const float*)d_in[13];
    float*       out            = (float*)d_out;

    f16* W16 = (f16*)d_ws;                               // [256][192] f16 = 96 KB

    const int B = in_sizes[0];

    ut_wconv_kernel<<<48, 256, 0, stream>>>(fc_w, W16);  // 12288 float4s

    const int grid = (B + 15) / 16;                      // 16 rows per block
    ut_fused_kernel<<<grid, 256, 0, stream>>>(
        user_input, emb, sc_country_idx, sc_country_emb,
        sc_device_idx, sc_device_emb, mf_tags_idx, mf_tags_emb,
        mf_history_idx, mf_history_emb, W16, fc_b, ln_g, ln_b, out, B);
}